// Round 1
// baseline (319.743 us; speedup 1.0000x reference)
//
#include <hip/hip_runtime.h>
#include <math.h>

// Problem constants
#define N384 384
#define NPIX 147456            // 384*384
#define LSTRIDE 385            // padded LDS line stride (float2) to break bank alignment
#define LINES 8                // lines (rows or cols) per block

__device__ __forceinline__ float2 cmul(float2 a, float2 b) {
    return make_float2(a.x*b.x - a.y*b.y, a.x*b.y + a.y*b.x);
}

// ---------------------------------------------------------------------------
// In-LDS batched 384-point Stockham FFT (autosort), 8 lines per 256-thread
// block. Radix sequence: 3, then 2^7. SGNI=-1 forward, +1 inverse
// (unnormalized). Data starts in b0 (layout line*LSTRIDE + elem), result ends
// in b0. Caller must __syncthreads() after loading b0.
// ---------------------------------------------------------------------------
template <int SGNI>
__device__ void fft384x8(float2* b0, float2* b1, int tid) {
    const float SGN = (float)SGNI;
    float2* src = b0;
    float2* dst = b1;
    const int line = tid >> 5;   // 0..7
    const int l32  = tid & 31;   // 0..31

    // ---- radix-3 stage: n=384, s=1, 128 butterflies/line ----
    {
        const float s3 = SGN * 0.86602540378443864676f;
        float2* L = src + line * LSTRIDE;
        float2* D = dst + line * LSTRIDE;
#pragma unroll
        for (int q = 0; q < 4; ++q) {
            int j = l32 + 32 * q;                  // 0..127
            float2 a0 = L[j], a1 = L[j + 128], a2 = L[j + 256];
            float t1x = a1.x + a2.x, t1y = a1.y + a2.y;
            float t2x = a1.x - a2.x, t2y = a1.y - a2.y;
            float2 bb0 = make_float2(a0.x + t1x, a0.y + t1y);
            float mx = a0.x - 0.5f * t1x, my = a0.y - 0.5f * t1y;
            float ux = -s3 * t2y, uy = s3 * t2x;
            float2 bb1 = make_float2(mx + ux, my + uy);
            float2 bb2 = make_float2(mx - ux, my - uy);
            float sn, cs;
            sincospif((float)j * (2.0f / 384.0f), &sn, &cs);   // angle = 2*pi*j/384
            float2 w  = make_float2(cs, SGN * sn);
            float2 w2 = cmul(w, w);
            D[3 * j]     = bb0;
            D[3 * j + 1] = cmul(bb1, w);
            D[3 * j + 2] = cmul(bb2, w2);
        }
    }
    __syncthreads();
    { float2* t = src; src = dst; dst = t; }

    // ---- 7 radix-2 stages: s = 3<<st, n = 128>>st, 192 butterflies/line ----
#pragma unroll
    for (int st = 0; st < 7; ++st) {
        const int s  = 3 << st;
        const int n  = 128 >> st;
        const int n2 = n >> 1;
        float2* L = src + line * LSTRIDE;
        float2* D = dst + line * LSTRIDE;
#pragma unroll
        for (int q = 0; q < 6; ++q) {
            int i = l32 + 32 * q;                  // 0..191
            int j = i / s;                         // constant s -> folded
            int k = i - j * s;
            float2 a = L[k + s * j];
            float2 b = L[k + s * j + s * n2];
            float sn, cs;
            sincospif((float)j * (2.0f / (float)n), &sn, &cs);
            float2 w = make_float2(cs, SGN * sn);
            float2 sum = make_float2(a.x + b.x, a.y + b.y);
            float2 dif = make_float2(a.x - b.x, a.y - b.y);
            D[k + s * (2 * j)]     = sum;
            D[k + s * (2 * j) + s] = cmul(dif, w);
        }
        __syncthreads();
        { float2* t = src; src = dst; dst = t; }
    }
    // 8 swaps total -> result in b0
}

// ---------------------------------------------------------------------------
// K1: forward row FFT of x (real input). 12 images x 48 row-groups.
// ---------------------------------------------------------------------------
__global__ __launch_bounds__(256) void k_fwd_rows(const float* __restrict__ x,
                                                  float2* __restrict__ F1) {
    __shared__ float2 sbuf[2][LINES * LSTRIDE];
    int img = blockIdx.y;                  // b*3+c
    int rg  = blockIdx.x;                  // 0..47
    int tid = threadIdx.x;
    const float* xim = x + (size_t)img * NPIX + (size_t)rg * 8 * 384;
    for (int idx = tid; idx < 8 * 384; idx += 256) {
        int line = idx / 384;
        int e    = idx - line * 384;
        sbuf[0][line * LSTRIDE + e] = make_float2(xim[idx], 0.0f);
    }
    __syncthreads();
    fft384x8<-1>(sbuf[0], sbuf[1], tid);
    float2* o = F1 + (size_t)img * NPIX + (size_t)rg * 8 * 384;
    for (int idx = tid; idx < 8 * 384; idx += 256) {
        int line = idx / 384;
        int e    = idx - line * 384;
        o[idx] = sbuf[0][line * LSTRIDE + e];
    }
}

// ---------------------------------------------------------------------------
// K2: forward column FFT. 12 images x 48 col-groups (8 cols each).
// ---------------------------------------------------------------------------
__global__ __launch_bounds__(256) void k_fwd_cols(const float2* __restrict__ In,
                                                  float2* __restrict__ Out) {
    __shared__ float2 sbuf[2][LINES * LSTRIDE];
    int img = blockIdx.y;
    int cg  = blockIdx.x;
    int tid = threadIdx.x;
    const float2* inim = In + (size_t)img * NPIX + cg * 8;
    int c = tid & 7, hb = tid >> 3;
    for (int q = 0; q < 12; ++q) {
        int h = hb + 32 * q;
        sbuf[0][c * LSTRIDE + h] = inim[(size_t)h * 384 + c];
    }
    __syncthreads();
    fft384x8<-1>(sbuf[0], sbuf[1], tid);
    float2* outim = Out + (size_t)img * NPIX + cg * 8;
    for (int q = 0; q < 12; ++q) {
        int h = hb + 32 * q;
        outim[(size_t)h * 384 + c] = sbuf[0][c * LSTRIDE + h];
    }
}

// ---------------------------------------------------------------------------
// K3: per-pixel attention MLP + log-Gabor filter bank -> attended[4,H,W].
// Works in the *shifted* coordinate system (h,w); reads raw fft2 output F2
// with the fftshift (all-axes!) folded into the index permutation.
// ---------------------------------------------------------------------------
__global__ __launch_bounds__(256) void k_attn(const float2* __restrict__ F2,
                                              const float* __restrict__ theta,
                                              const float* __restrict__ sigma,
                                              const float* __restrict__ f0,
                                              const float* __restrict__ theta0,
                                              const float* __restrict__ aw1,
                                              const float* __restrict__ ab1,
                                              const float* __restrict__ aw2,
                                              const float* __restrict__ ab2,
                                              float2* __restrict__ A) {
    int p = blockIdx.x * 256 + threadIdx.x;   // 0..147455
    int h = p / 384;
    int w = p - h * 384;
    int hs = h + 192; if (hs >= 384) hs -= 384;
    int ws = w + 192; if (ws >= 384) ws -= 384;

    float2 xf[4][3];
    float  mag[4][3];
#pragma unroll
    for (int b = 0; b < 4; ++b) {
        int bp = (b + 2) & 3;
#pragma unroll
        for (int c = 0; c < 3; ++c) {
            int cp = c + 2; if (cp >= 3) cp -= 3;
            float2 v = F2[(size_t)(bp * 3 + cp) * NPIX + (size_t)hs * 384 + ws];
            xf[b][c]  = v;
            mag[b][c] = sqrtf(v.x * v.x + v.y * v.y);
        }
    }

    // log-Gabor bank at this pixel (shifted grid coords)
    float yy = -1.0f + 2.0f * (float)h / 383.0f;
    float xx = -1.0f + 2.0f * (float)w / 383.0f;
    float r   = sqrtf(xx * xx + yy * yy + 1e-6f);
    float phi = atan2f(yy, xx);
    float filt[3][3][3];
#pragma unroll
    for (int s = 0; s < 3; ++s)
#pragma unroll
        for (int co = 0; co < 3; ++co)
#pragma unroll
            for (int d = 0; d < 3; ++d) {
                int idx = (s * 3 + co) * 3 + d;
                float lf0 = logf(f0[idx]);
                float ls  = logf(sigma[idx]);
                float lr  = logf(r - lf0);
                float lg  = expf(-(lr * lr) / (2.0f * ls * ls));
                float dphi = phi - theta[idx];
                float t0   = theta0[idx];
                float ang  = expf(-(dphi * dphi) / (2.0f * t0 * t0));
                filt[s][co][d] = lg * ang;
            }

#pragma unroll
    for (int b = 0; b < 4; ++b) {
        float lgt[9];
#pragma unroll
        for (int j = 0; j < 9; ++j) lgt[j] = ab2[j];
        for (int o = 0; o < 64; ++o) {
            float hv = ab1[o] + aw1[o * 3 + 0] * mag[b][0]
                              + aw1[o * 3 + 1] * mag[b][1]
                              + aw1[o * 3 + 2] * mag[b][2];
            hv = fmaxf(hv, 0.0f);
#pragma unroll
            for (int j = 0; j < 9; ++j) lgt[j] += aw2[j * 64 + o] * hv;
        }
        float mxv = lgt[0];
#pragma unroll
        for (int j = 1; j < 9; ++j) mxv = fmaxf(mxv, lgt[j]);
        float se = 0.0f;
#pragma unroll
        for (int j = 0; j < 9; ++j) { lgt[j] = expf(lgt[j] - mxv); se += lgt[j]; }
        float inv = 1.0f / se;

        float2 acc = make_float2(0.0f, 0.0f);
#pragma unroll
        for (int d = 0; d < 3; ++d) {
            float wg = 0.0f;
#pragma unroll
            for (int s = 0; s < 3; ++s)
#pragma unroll
                for (int co = 0; co < 3; ++co)
                    wg += lgt[s * 3 + co] * filt[s][co][d];
            wg *= inv;
            acc.x += xf[b][d].x * wg;
            acc.y += xf[b][d].y * wg;
        }
        A[(size_t)b * NPIX + p] = acc;
    }
}

// ---------------------------------------------------------------------------
// K6: 3x3 conv, pad 1. xsp[b][o][h][w]
// ---------------------------------------------------------------------------
__global__ __launch_bounds__(256) void k_conv(const float* __restrict__ x,
                                              const float* __restrict__ cw,
                                              float* __restrict__ xsp) {
    int p = blockIdx.x * 256 + threadIdx.x;   // 4*3*147456 = 1769472
    int w = p % 384;
    int t = p / 384;
    int h = t % 384; t /= 384;
    int o = t % 3;
    int b = t / 3;
    float acc = 0.0f;
    const float* xb = x + (size_t)b * 3 * NPIX;
#pragma unroll
    for (int ci = 0; ci < 3; ++ci) {
        const float* xc = xb + (size_t)ci * NPIX;
#pragma unroll
        for (int kh = 0; kh < 3; ++kh) {
            int hh = h + kh - 1;
            if (hh < 0 || hh >= 384) continue;
#pragma unroll
            for (int kw = 0; kw < 3; ++kw) {
                int ww = w + kw - 1;
                if (ww < 0 || ww >= 384) continue;
                acc += xc[(size_t)hh * 384 + ww] * cw[((o * 3 + ci) * 3 + kh) * 3 + kw];
            }
        }
    }
    xsp[p] = acc;
}

// ---------------------------------------------------------------------------
// K4: inverse row FFT of masked attended spectra. 36 images (co',b',d').
// ifftshift (h,w) + band mask folded into loads.
// ---------------------------------------------------------------------------
__global__ __launch_bounds__(256) void k_inv_rows(const float2* __restrict__ A,
                                                  const float* __restrict__ band,
                                                  float2* __restrict__ G1) {
    __shared__ float2 sbuf[2][LINES * LSTRIDE];
    int ii  = blockIdx.y;                  // co'*12 + b'*3 + d'
    int rg  = blockIdx.x;
    int tid = threadIdx.x;
    int cop = ii / 12;
    int bp  = (ii / 3) % 4;
    int dp  = ii % 3;
    float bnd0 = band[(cop * 3 + dp) * 2 + 0];
    float bnd1 = band[(cop * 3 + dp) * 2 + 1];
    int sidx = (int)floorf((bnd0 + 1.0f) / 2.0f * 384.0f);
    int eidx = (int)floorf((bnd1 + 1.0f) / 2.0f * 384.0f);
    const float2* Ab = A + (size_t)bp * NPIX;

    for (int idx = tid; idx < 8 * 384; idx += 256) {
        int line = idx / 384;
        int w    = idx - line * 384;
        int h    = rg * 8 + line;
        int hsv = h + 192; if (hsv >= 384) hsv -= 384;
        int wsv = w + 192; if (wsv >= 384) wsv -= 384;
        bool m = (hsv >= sidx) && (hsv < eidx) && (wsv >= sidx) && (wsv < eidx);
        float2 v = make_float2(0.0f, 0.0f);
        if (m) v = Ab[(size_t)hsv * 384 + wsv];
        sbuf[0][line * LSTRIDE + w] = v;
    }
    __syncthreads();
    fft384x8<1>(sbuf[0], sbuf[1], tid);
    float2* o = G1 + (size_t)ii * NPIX + (size_t)rg * 8 * 384;
    for (int idx = tid; idx < 8 * 384; idx += 256) {
        int line = idx / 384;
        int e    = idx - line * 384;
        o[idx] = sbuf[0][line * LSTRIDE + e];
    }
}

// ---------------------------------------------------------------------------
// K5: inverse column FFT + final combine. Each of 36 images writes its 4
// a-broadcast replicas of out = mix*ifft2(...).real + (1-mix)*xsp[b,d].
// ---------------------------------------------------------------------------
__global__ __launch_bounds__(256) void k_inv_cols_combine(const float2* __restrict__ G1,
                                                          const float* __restrict__ xsp,
                                                          const float* __restrict__ mixing,
                                                          float* __restrict__ out) {
    __shared__ float2 sbuf[2][LINES * LSTRIDE];
    int ii  = blockIdx.y;
    int cg  = blockIdx.x;
    int tid = threadIdx.x;
    const float2* inim = G1 + (size_t)ii * NPIX + cg * 8;
    int c = tid & 7, hb = tid >> 3;
    for (int q = 0; q < 12; ++q) {
        int h = hb + 32 * q;
        sbuf[0][c * LSTRIDE + h] = inim[(size_t)h * 384 + c];
    }
    __syncthreads();
    fft384x8<1>(sbuf[0], sbuf[1], tid);

    int cop = ii / 12, bp = (ii / 3) % 4, dp = ii % 3;
    int co = cop + 2; if (co >= 3) co -= 3;     // (cop+2)%3
    int b  = (bp + 2) & 3;
    int d  = dp + 2;  if (d >= 3) d -= 3;
    float mix = mixing[0];
    const float invn2 = 1.0f / 147456.0f;
    const float* xs = xsp + (size_t)(b * 3 + d) * NPIX;
    float* obase = out + (size_t)(co * 12 + b * 3 + d) * NPIX;
    for (int q = 0; q < 12; ++q) {
        int h = hb + 32 * q;
        int w = cg * 8 + c;
        float g   = sbuf[0][c * LSTRIDE + h].x * invn2;
        float val = mix * g + (1.0f - mix) * xs[(size_t)h * 384 + w];
        size_t off = (size_t)h * 384 + w;
#pragma unroll
        for (int a = 0; a < 4; ++a)
            obase[off + (size_t)a * 5308416] = val;   // a stride = 36*147456
    }
}

// ---------------------------------------------------------------------------
extern "C" void kernel_launch(void* const* d_in, const int* in_sizes, int n_in,
                              void* d_out, int out_size, void* d_ws, size_t ws_size,
                              hipStream_t stream) {
    const float* x      = (const float*)d_in[0];
    const float* theta  = (const float*)d_in[1];
    const float* sigma  = (const float*)d_in[2];
    const float* f0     = (const float*)d_in[3];
    const float* theta0 = (const float*)d_in[4];
    const float* aw1    = (const float*)d_in[5];
    const float* ab1    = (const float*)d_in[6];
    const float* aw2    = (const float*)d_in[7];
    const float* ab2    = (const float*)d_in[8];
    const float* cw     = (const float*)d_in[9];
    const float* mixing = (const float*)d_in[10];
    const float* band   = (const float*)d_in[11];
    float* out = (float*)d_out;

    // Workspace layout (float2 units), with reuse:
    //   [0, 12*NPIX)   F1 (dead after K2)       \  overlaid by
    //   [12, 24*NPIX)  F2 (dead after K3)       /  G1 [0, 36*NPIX)
    //   [36, 40*NPIX)  A  (attended)
    //   [40*NPIX ...)  xsp (floats, 12*NPIX floats)
    // Total: 40*NPIX*8 + 12*NPIX*4 = 54,263,808 bytes.
    float2* F1 = (float2*)d_ws;
    float2* F2 = F1 + (size_t)12 * NPIX;
    float2* G1 = (float2*)d_ws;
    float2* A  = (float2*)d_ws + (size_t)36 * NPIX;
    float*  xsp = (float*)((float2*)d_ws + (size_t)40 * NPIX);

    k_fwd_rows<<<dim3(48, 12), 256, 0, stream>>>(x, F1);
    k_fwd_cols<<<dim3(48, 12), 256, 0, stream>>>(F1, F2);
    k_attn<<<576, 256, 0, stream>>>(F2, theta, sigma, f0, theta0,
                                    aw1, ab1, aw2, ab2, A);
    k_conv<<<6912, 256, 0, stream>>>(x, cw, xsp);
    k_inv_rows<<<dim3(48, 36), 256, 0, stream>>>(A, band, G1);
    k_inv_cols_combine<<<dim3(48, 36), 256, 0, stream>>>(G1, xsp, mixing, out);
}

// Round 2
// 311.355 us; speedup vs baseline: 1.0269x; 1.0269x over previous
//
#include <hip/hip_runtime.h>
#include <math.h>

// Problem constants
#define N384 384
#define NPIX 147456            // 384*384
#define LSTRIDE 385            // padded LDS line stride (float2) to break bank alignment
#define LINES 8                // lines (rows or cols) per block

__device__ __forceinline__ float2 cmul(float2 a, float2 b) {
    return make_float2(a.x*b.x - a.y*b.y, a.x*b.y + a.y*b.x);
}

// ---------------------------------------------------------------------------
// In-LDS batched 384-point Stockham FFT (autosort), 8 lines per 256-thread
// block. Radix sequence: 3, then 2^7. SGNI=-1 forward, +1 inverse
// (unnormalized). Data starts in b0 (layout line*LSTRIDE + elem), result ends
// in b0. Caller must __syncthreads() after loading b0.
// ---------------------------------------------------------------------------
template <int SGNI>
__device__ void fft384x8(float2* b0, float2* b1, int tid) {
    const float SGN = (float)SGNI;
    float2* src = b0;
    float2* dst = b1;
    const int line = tid >> 5;   // 0..7
    const int l32  = tid & 31;   // 0..31

    // ---- radix-3 stage: n=384, s=1, 128 butterflies/line ----
    {
        const float s3 = SGN * 0.86602540378443864676f;
        float2* L = src + line * LSTRIDE;
        float2* D = dst + line * LSTRIDE;
#pragma unroll
        for (int q = 0; q < 4; ++q) {
            int j = l32 + 32 * q;                  // 0..127
            float2 a0 = L[j], a1 = L[j + 128], a2 = L[j + 256];
            float t1x = a1.x + a2.x, t1y = a1.y + a2.y;
            float t2x = a1.x - a2.x, t2y = a1.y - a2.y;
            float2 bb0 = make_float2(a0.x + t1x, a0.y + t1y);
            float mx = a0.x - 0.5f * t1x, my = a0.y - 0.5f * t1y;
            float ux = -s3 * t2y, uy = s3 * t2x;
            float2 bb1 = make_float2(mx + ux, my + uy);
            float2 bb2 = make_float2(mx - ux, my - uy);
            float sn, cs;
            sincospif((float)j * (2.0f / 384.0f), &sn, &cs);   // angle = 2*pi*j/384
            float2 w  = make_float2(cs, SGN * sn);
            float2 w2 = cmul(w, w);
            D[3 * j]     = bb0;
            D[3 * j + 1] = cmul(bb1, w);
            D[3 * j + 2] = cmul(bb2, w2);
        }
    }
    __syncthreads();
    { float2* t = src; src = dst; dst = t; }

    // ---- 7 radix-2 stages: s = 3<<st, n = 128>>st, 192 butterflies/line ----
#pragma unroll
    for (int st = 0; st < 7; ++st) {
        const int s  = 3 << st;
        const int n  = 128 >> st;
        const int n2 = n >> 1;
        float2* L = src + line * LSTRIDE;
        float2* D = dst + line * LSTRIDE;
#pragma unroll
        for (int q = 0; q < 6; ++q) {
            int i = l32 + 32 * q;                  // 0..191
            int j = i / s;
            int k = i - j * s;
            float2 a = L[k + s * j];
            float2 b = L[k + s * j + s * n2];
            float sn, cs;
            sincospif((float)j * (2.0f / (float)n), &sn, &cs);
            float2 w = make_float2(cs, SGN * sn);
            float2 sum = make_float2(a.x + b.x, a.y + b.y);
            float2 dif = make_float2(a.x - b.x, a.y - b.y);
            D[k + s * (2 * j)]     = sum;
            D[k + s * (2 * j) + s] = cmul(dif, w);
        }
        __syncthreads();
        { float2* t = src; src = dst; dst = t; }
    }
    // 8 swaps total -> result in b0
}

// ---------------------------------------------------------------------------
// K1: forward row FFT of x (real input). 12 images x 48 row-groups.
// ---------------------------------------------------------------------------
__global__ __launch_bounds__(256) void k_fwd_rows(const float* __restrict__ x,
                                                  float2* __restrict__ F1) {
    __shared__ float2 sbuf[2][LINES * LSTRIDE];
    int img = blockIdx.y;                  // b*3+c
    int rg  = blockIdx.x;                  // 0..47
    int tid = threadIdx.x;
    const float* xim = x + (size_t)img * NPIX + (size_t)rg * 8 * 384;
    for (int idx = tid; idx < 8 * 384; idx += 256) {
        int line = idx / 384;
        int e    = idx - line * 384;
        sbuf[0][line * LSTRIDE + e] = make_float2(xim[idx], 0.0f);
    }
    __syncthreads();
    fft384x8<-1>(sbuf[0], sbuf[1], tid);
    float2* o = F1 + (size_t)img * NPIX + (size_t)rg * 8 * 384;
    for (int idx = tid; idx < 8 * 384; idx += 256) {
        int line = idx / 384;
        int e    = idx - line * 384;
        o[idx] = sbuf[0][line * LSTRIDE + e];
    }
}

// ---------------------------------------------------------------------------
// K2: forward column FFT. 12 images x 48 col-groups (8 cols each).
// ---------------------------------------------------------------------------
__global__ __launch_bounds__(256) void k_fwd_cols(const float2* __restrict__ In,
                                                  float2* __restrict__ Out) {
    __shared__ float2 sbuf[2][LINES * LSTRIDE];
    int img = blockIdx.y;
    int cg  = blockIdx.x;
    int tid = threadIdx.x;
    const float2* inim = In + (size_t)img * NPIX + cg * 8;
    int c = tid & 7, hb = tid >> 3;
    for (int q = 0; q < 12; ++q) {
        int h = hb + 32 * q;
        sbuf[0][c * LSTRIDE + h] = inim[(size_t)h * 384 + c];
    }
    __syncthreads();
    fft384x8<-1>(sbuf[0], sbuf[1], tid);
    float2* outim = Out + (size_t)img * NPIX + cg * 8;
    for (int q = 0; q < 12; ++q) {
        int h = hb + 32 * q;
        outim[(size_t)h * 384 + c] = sbuf[0][c * LSTRIDE + h];
    }
}

// ---------------------------------------------------------------------------
// K3: per-pixel attention MLP + log-Gabor filter bank -> attended[4,H,W]
// (stored in the SHIFTED frame: A[b][h][w] = attended at shifted coords).
// ---------------------------------------------------------------------------
__global__ __launch_bounds__(256) void k_attn(const float2* __restrict__ F2,
                                              const float* __restrict__ theta,
                                              const float* __restrict__ sigma,
                                              const float* __restrict__ f0,
                                              const float* __restrict__ theta0,
                                              const float* __restrict__ aw1,
                                              const float* __restrict__ ab1,
                                              const float* __restrict__ aw2,
                                              const float* __restrict__ ab2,
                                              float2* __restrict__ A) {
    int p = blockIdx.x * 256 + threadIdx.x;   // 0..147455
    int h = p / 384;
    int w = p - h * 384;
    int hs = h + 192; if (hs >= 384) hs -= 384;
    int ws = w + 192; if (ws >= 384) ws -= 384;

    float2 xf[4][3];
    float  mag[4][3];
#pragma unroll
    for (int b = 0; b < 4; ++b) {
        int bp = (b + 2) & 3;
#pragma unroll
        for (int c = 0; c < 3; ++c) {
            int cp = c + 2; if (cp >= 3) cp -= 3;
            float2 v = F2[(size_t)(bp * 3 + cp) * NPIX + (size_t)hs * 384 + ws];
            xf[b][c]  = v;
            mag[b][c] = sqrtf(v.x * v.x + v.y * v.y);
        }
    }

    float yy = -1.0f + 2.0f * (float)h / 383.0f;
    float xx = -1.0f + 2.0f * (float)w / 383.0f;
    float r   = sqrtf(xx * xx + yy * yy + 1e-6f);
    float phi = atan2f(yy, xx);
    float filt[3][3][3];
#pragma unroll
    for (int s = 0; s < 3; ++s)
#pragma unroll
        for (int co = 0; co < 3; ++co)
#pragma unroll
            for (int d = 0; d < 3; ++d) {
                int idx = (s * 3 + co) * 3 + d;
                float lf0 = logf(f0[idx]);
                float ls  = logf(sigma[idx]);
                float lr  = logf(r - lf0);
                float lg  = expf(-(lr * lr) / (2.0f * ls * ls));
                float dphi = phi - theta[idx];
                float t0   = theta0[idx];
                float ang  = expf(-(dphi * dphi) / (2.0f * t0 * t0));
                filt[s][co][d] = lg * ang;
            }

#pragma unroll
    for (int b = 0; b < 4; ++b) {
        float lgt[9];
#pragma unroll
        for (int j = 0; j < 9; ++j) lgt[j] = ab2[j];
        for (int o = 0; o < 64; ++o) {
            float hv = ab1[o] + aw1[o * 3 + 0] * mag[b][0]
                              + aw1[o * 3 + 1] * mag[b][1]
                              + aw1[o * 3 + 2] * mag[b][2];
            hv = fmaxf(hv, 0.0f);
#pragma unroll
            for (int j = 0; j < 9; ++j) lgt[j] += aw2[j * 64 + o] * hv;
        }
        float mxv = lgt[0];
#pragma unroll
        for (int j = 1; j < 9; ++j) mxv = fmaxf(mxv, lgt[j]);
        float se = 0.0f;
#pragma unroll
        for (int j = 0; j < 9; ++j) { lgt[j] = expf(lgt[j] - mxv); se += lgt[j]; }
        float inv = 1.0f / se;

        float2 acc = make_float2(0.0f, 0.0f);
#pragma unroll
        for (int d = 0; d < 3; ++d) {
            float wg = 0.0f;
#pragma unroll
            for (int s = 0; s < 3; ++s)
#pragma unroll
                for (int co = 0; co < 3; ++co)
                    wg += lgt[s * 3 + co] * filt[s][co][d];
            wg *= inv;
            acc.x += xf[b][d].x * wg;
            acc.y += xf[b][d].y * wg;
        }
        A[(size_t)b * NPIX + p] = acc;
    }
}

// ---------------------------------------------------------------------------
// K6: 3x3 conv, pad 1. xsp[b][o][h][w]
// ---------------------------------------------------------------------------
__global__ __launch_bounds__(256) void k_conv(const float* __restrict__ x,
                                              const float* __restrict__ cw,
                                              float* __restrict__ xsp) {
    int p = blockIdx.x * 256 + threadIdx.x;   // 1769472
    int w = p % 384;
    int t = p / 384;
    int h = t % 384; t /= 384;
    int o = t % 3;
    int b = t / 3;
    float acc = 0.0f;
    const float* xb = x + (size_t)b * 3 * NPIX;
#pragma unroll
    for (int ci = 0; ci < 3; ++ci) {
        const float* xc = xb + (size_t)ci * NPIX;
#pragma unroll
        for (int kh = 0; kh < 3; ++kh) {
            int hh = h + kh - 1;
            if (hh < 0 || hh >= 384) continue;
#pragma unroll
            for (int kw = 0; kw < 3; ++kw) {
                int ww = w + kw - 1;
                if (ww < 0 || ww >= 384) continue;
                acc += xc[(size_t)hh * 384 + ww] * cw[((o * 3 + ci) * 3 + kh) * 3 + kw];
            }
        }
    }
    xsp[p] = acc;
}

// ---------------------------------------------------------------------------
// K4': masked inverse ROW FFTs, band rows only, compact output.
// Band indices live in [192,384) -> grid.x = 24 row-groups of 8 covering
// rows 192..383; blocks with no overlap exit immediately.
// ifftshift folded analytically: G1c[w] stores (-1)^w * sum_{w' in band}
// A[h'][w'] e^{+2pi i w w'/384}  (A already in shifted frame).
// Layout: G1c[ii][h'-sidx][w], ii = cop*12 + bp*3 + dp.
// ---------------------------------------------------------------------------
__global__ __launch_bounds__(256) void k_masked_rows(const float2* __restrict__ A,
                                                     const float* __restrict__ band,
                                                     float2* __restrict__ G1c) {
    int ii  = blockIdx.y;                  // 0..35
    int rg  = blockIdx.x;                  // 0..23
    int cop = ii / 12;
    int bp  = (ii / 3) % 4;
    int dp  = ii % 3;
    int pidx = (cop * 3 + dp) * 2;
    int sidx = (int)floorf((band[pidx + 0] + 1.0f) * 0.5f * 384.0f);
    int eidx = (int)floorf((band[pidx + 1] + 1.0f) * 0.5f * 384.0f);
    if (eidx <= sidx) return;              // empty mask -> G = 0 contribution
    int h0 = 192 + rg * 8;
    if (h0 + 8 <= sidx || h0 >= eidx) return;

    __shared__ float2 sbuf[2][LINES * LSTRIDE];
    int tid = threadIdx.x;
    const float2* Ab = A + (size_t)bp * NPIX;
    for (int idx = tid; idx < 8 * 384; idx += 256) {
        int line = idx / 384;
        int w    = idx - line * 384;
        int h    = h0 + line;
        bool m = (h >= sidx) && (h < eidx) && (w >= sidx) && (w < eidx);
        float2 v = make_float2(0.0f, 0.0f);
        if (m) v = Ab[(size_t)h * 384 + w];
        sbuf[0][line * LSTRIDE + w] = v;
    }
    __syncthreads();
    fft384x8<1>(sbuf[0], sbuf[1], tid);
    for (int idx = tid; idx < 8 * 384; idx += 256) {
        int line = idx / 384;
        int w    = idx - line * 384;
        int h    = h0 + line;
        if (h >= sidx && h < eidx) {
            float2 v = sbuf[0][line * LSTRIDE + w];
            if (w & 1) { v.x = -v.x; v.y = -v.y; }          // fold (-1)^w
            G1c[((size_t)ii * 192 + (h - sidx)) * 384 + w] = v;
        }
    }
}

// ---------------------------------------------------------------------------
// K5': direct column DFT over the <=192 band rows + final combine.
// out[h,w] = mix * (-1)^h/N^2 * Re( sum_{h' in band} e^{+2pi i h h'/384} g1[h',w] )
//          + (1-mix) * xsp[b,d,h,w]
// written to all 4 'a' broadcast replicas. No LDS; acc[24] in registers.
// grid: x = 24 (12 w-tiles x 2 h-halves), y = 36 images.
// ---------------------------------------------------------------------------
__global__ __launch_bounds__(256) void k_col_dft_combine(const float2* __restrict__ G1c,
                                                         const float* __restrict__ band,
                                                         const float* __restrict__ xsp,
                                                         const float* __restrict__ mixing,
                                                         float* __restrict__ out) {
    int ii = blockIdx.y;
    int wt = blockIdx.x % 12;
    int hh = blockIdx.x / 12;
    int tid = threadIdx.x;
    int wl = tid & 31;
    int hg = tid >> 5;
    int w  = wt * 32 + wl;
    int hstart = hh * 192 + hg * 24;

    int cop = ii / 12;
    int bp  = (ii / 3) % 4;
    int dp  = ii % 3;
    int pidx = (cop * 3 + dp) * 2;
    int sidx = (int)floorf((band[pidx + 0] + 1.0f) * 0.5f * 384.0f);
    int eidx = (int)floorf((band[pidx + 1] + 1.0f) * 0.5f * 384.0f);

    float acc[24];
#pragma unroll
    for (int k = 0; k < 24; ++k) acc[k] = 0.0f;

    const float2* g = G1c + ((size_t)ii * 192) * 384 + w;
    for (int hp = sidx; hp < eidx; ++hp) {
        float2 gv = g[(size_t)(hp - sidx) * 384];
        int k0 = (hp * hstart) % 384;
        float sn, cs;
        sincospif((float)k0 * (2.0f / 384.0f), &sn, &cs);   // e^{2pi i hp*hstart/384}
        float tx = cs, ty = sn;
        float ssn, scs;
        sincospif((float)hp * (2.0f / 384.0f), &ssn, &scs); // step e^{2pi i hp/384}
#pragma unroll
        for (int k = 0; k < 24; ++k) {
            acc[k] += tx * gv.x - ty * gv.y;
            float ntx = tx * scs - ty * ssn;
            ty = tx * ssn + ty * scs;
            tx = ntx;
        }
    }

    int co = cop + 2; if (co >= 3) co -= 3;
    int b  = (bp + 2) & 3;
    int d  = dp + 2;  if (d >= 3) d -= 3;
    float mix = mixing[0];
    const float invn2 = 1.0f / 147456.0f;
    const float* xs = xsp + (size_t)(b * 3 + d) * NPIX;
    float* obase = out + (size_t)(co * 12 + b * 3 + d) * NPIX;
#pragma unroll
    for (int k = 0; k < 24; ++k) {
        int h = hstart + k;
        float sgn = (h & 1) ? -invn2 : invn2;               // fold (-1)^h / N^2
        size_t off = (size_t)h * 384 + w;
        float val = mix * (acc[k] * sgn) + (1.0f - mix) * xs[off];
#pragma unroll
        for (int a = 0; a < 4; ++a)
            obase[off + (size_t)a * 5308416] = val;         // a stride = 36*NPIX
    }
}

// ---------------------------------------------------------------------------
extern "C" void kernel_launch(void* const* d_in, const int* in_sizes, int n_in,
                              void* d_out, int out_size, void* d_ws, size_t ws_size,
                              hipStream_t stream) {
    const float* x      = (const float*)d_in[0];
    const float* theta  = (const float*)d_in[1];
    const float* sigma  = (const float*)d_in[2];
    const float* f0     = (const float*)d_in[3];
    const float* theta0 = (const float*)d_in[4];
    const float* aw1    = (const float*)d_in[5];
    const float* ab1    = (const float*)d_in[6];
    const float* aw2    = (const float*)d_in[7];
    const float* ab2    = (const float*)d_in[8];
    const float* cw     = (const float*)d_in[9];
    const float* mixing = (const float*)d_in[10];
    const float* band   = (const float*)d_in[11];
    float* out = (float*)d_out;

    // Workspace layout (float2 units), with reuse:
    //   [0, 12*NPIX)   F1 (dead after K2)   \  overlaid by G1c [0, 18*NPIX)
    //   [12, 24*NPIX)  F2 (dead after K3)   /  (36*192*384 float2 = 18*NPIX)
    //   [36, 40*NPIX)  A  (attended, shifted frame)
    //   [40*NPIX ...)  xsp (12*NPIX floats)
    float2* F1  = (float2*)d_ws;
    float2* F2  = F1 + (size_t)12 * NPIX;
    float2* G1c = (float2*)d_ws;
    float2* A   = (float2*)d_ws + (size_t)36 * NPIX;
    float*  xsp = (float*)((float2*)d_ws + (size_t)40 * NPIX);

    k_fwd_rows<<<dim3(48, 12), 256, 0, stream>>>(x, F1);
    k_fwd_cols<<<dim3(48, 12), 256, 0, stream>>>(F1, F2);
    k_attn<<<576, 256, 0, stream>>>(F2, theta, sigma, f0, theta0,
                                    aw1, ab1, aw2, ab2, A);
    k_conv<<<6912, 256, 0, stream>>>(x, cw, xsp);
    k_masked_rows<<<dim3(24, 36), 256, 0, stream>>>(A, band, G1c);
    k_col_dft_combine<<<dim3(24, 36), 256, 0, stream>>>(G1c, band, xsp, mixing, out);
}

// Round 3
// 257.259 us; speedup vs baseline: 1.2429x; 1.2103x over previous
//
#include <hip/hip_runtime.h>
#include <math.h>

// Problem constants
#define N384 384
#define NPIX 147456            // 384*384
#define LSTRIDE 385            // padded LDS line stride (float2) to break bank alignment
#define LINES 8                // lines (rows or cols) per block

__device__ __forceinline__ float2 cmul(float2 a, float2 b) {
    return make_float2(a.x*b.x - a.y*b.y, a.x*b.y + a.y*b.x);
}

// ---------------------------------------------------------------------------
// In-LDS batched 384-point Stockham FFT (autosort), 8 lines per 256-thread
// block. Radix sequence: 3, then 2^7. SGNI=-1 forward, +1 inverse
// (unnormalized). Data starts in b0 (layout line*LSTRIDE + elem), result ends
// in b0. Caller must __syncthreads() after loading b0.
// ---------------------------------------------------------------------------
template <int SGNI>
__device__ void fft384x8(float2* b0, float2* b1, int tid) {
    const float SGN = (float)SGNI;
    float2* src = b0;
    float2* dst = b1;
    const int line = tid >> 5;   // 0..7
    const int l32  = tid & 31;   // 0..31

    // ---- radix-3 stage: n=384, s=1, 128 butterflies/line ----
    {
        const float s3 = SGN * 0.86602540378443864676f;
        float2* L = src + line * LSTRIDE;
        float2* D = dst + line * LSTRIDE;
#pragma unroll
        for (int q = 0; q < 4; ++q) {
            int j = l32 + 32 * q;                  // 0..127
            float2 a0 = L[j], a1 = L[j + 128], a2 = L[j + 256];
            float t1x = a1.x + a2.x, t1y = a1.y + a2.y;
            float t2x = a1.x - a2.x, t2y = a1.y - a2.y;
            float2 bb0 = make_float2(a0.x + t1x, a0.y + t1y);
            float mx = a0.x - 0.5f * t1x, my = a0.y - 0.5f * t1y;
            float ux = -s3 * t2y, uy = s3 * t2x;
            float2 bb1 = make_float2(mx + ux, my + uy);
            float2 bb2 = make_float2(mx - ux, my - uy);
            float sn, cs;
            sincospif((float)j * (2.0f / 384.0f), &sn, &cs);
            float2 w  = make_float2(cs, SGN * sn);
            float2 w2 = cmul(w, w);
            D[3 * j]     = bb0;
            D[3 * j + 1] = cmul(bb1, w);
            D[3 * j + 2] = cmul(bb2, w2);
        }
    }
    __syncthreads();
    { float2* t = src; src = dst; dst = t; }

    // ---- 7 radix-2 stages ----
#pragma unroll
    for (int st = 0; st < 7; ++st) {
        const int s  = 3 << st;
        const int n  = 128 >> st;
        const int n2 = n >> 1;
        float2* L = src + line * LSTRIDE;
        float2* D = dst + line * LSTRIDE;
#pragma unroll
        for (int q = 0; q < 6; ++q) {
            int i = l32 + 32 * q;                  // 0..191
            int j = i / s;
            int k = i - j * s;
            float2 a = L[k + s * j];
            float2 b = L[k + s * j + s * n2];
            float sn, cs;
            sincospif((float)j * (2.0f / (float)n), &sn, &cs);
            float2 w = make_float2(cs, SGN * sn);
            float2 sum = make_float2(a.x + b.x, a.y + b.y);
            float2 dif = make_float2(a.x - b.x, a.y - b.y);
            D[k + s * (2 * j)]     = sum;
            D[k + s * (2 * j) + s] = cmul(dif, w);
        }
        __syncthreads();
        { float2* t = src; src = dst; dst = t; }
    }
}

// ---------------------------------------------------------------------------
// K1: forward row FFT of x (real input). 12 images x 48 row-groups.
// ---------------------------------------------------------------------------
__global__ __launch_bounds__(256) void k_fwd_rows(const float* __restrict__ x,
                                                  float2* __restrict__ F1) {
    __shared__ float2 sbuf[2][LINES * LSTRIDE];
    int img = blockIdx.y;
    int rg  = blockIdx.x;
    int tid = threadIdx.x;
    const float* xim = x + (size_t)img * NPIX + (size_t)rg * 8 * 384;
    for (int idx = tid; idx < 8 * 384; idx += 256) {
        int line = idx / 384;
        int e    = idx - line * 384;
        sbuf[0][line * LSTRIDE + e] = make_float2(xim[idx], 0.0f);
    }
    __syncthreads();
    fft384x8<-1>(sbuf[0], sbuf[1], tid);
    float2* o = F1 + (size_t)img * NPIX + (size_t)rg * 8 * 384;
    for (int idx = tid; idx < 8 * 384; idx += 256) {
        int line = idx / 384;
        int e    = idx - line * 384;
        o[idx] = sbuf[0][line * LSTRIDE + e];
    }
}

// ---------------------------------------------------------------------------
// K2: forward column FFT. 12 images x 48 col-groups (8 cols each).
// ---------------------------------------------------------------------------
__global__ __launch_bounds__(256) void k_fwd_cols(const float2* __restrict__ In,
                                                  float2* __restrict__ Out) {
    __shared__ float2 sbuf[2][LINES * LSTRIDE];
    int img = blockIdx.y;
    int cg  = blockIdx.x;
    int tid = threadIdx.x;
    const float2* inim = In + (size_t)img * NPIX + cg * 8;
    int c = tid & 7, hb = tid >> 3;
    for (int q = 0; q < 12; ++q) {
        int h = hb + 32 * q;
        sbuf[0][c * LSTRIDE + h] = inim[(size_t)h * 384 + c];
    }
    __syncthreads();
    fft384x8<-1>(sbuf[0], sbuf[1], tid);
    float2* outim = Out + (size_t)img * NPIX + cg * 8;
    for (int q = 0; q < 12; ++q) {
        int h = hb + 32 * q;
        outim[(size_t)h * 384 + c] = sbuf[0][c * LSTRIDE + h];
    }
}

// ---------------------------------------------------------------------------
// K3: per-pixel attention MLP + log-Gabor filter bank -> attended[4,H,W]
// (stored in the SHIFTED frame). MLP restructured: o-loop outer, all 4 b
// inner -> weight loads hoisted (4x fewer), uniform-address scalar loads.
// ---------------------------------------------------------------------------
__global__ __launch_bounds__(256) void k_attn(const float2* __restrict__ F2,
                                              const float* __restrict__ theta,
                                              const float* __restrict__ sigma,
                                              const float* __restrict__ f0,
                                              const float* __restrict__ theta0,
                                              const float* __restrict__ aw1,
                                              const float* __restrict__ ab1,
                                              const float* __restrict__ aw2,
                                              const float* __restrict__ ab2,
                                              float2* __restrict__ A) {
    int p = blockIdx.x * 256 + threadIdx.x;
    int h = p / 384;
    int w = p - h * 384;
    int hs = h + 192; if (hs >= 384) hs -= 384;
    int ws = w + 192; if (ws >= 384) ws -= 384;

    float2 xf[4][3];
    float  mag[4][3];
#pragma unroll
    for (int b = 0; b < 4; ++b) {
        int bp = (b + 2) & 3;
#pragma unroll
        for (int c = 0; c < 3; ++c) {
            int cp = c + 2; if (cp >= 3) cp -= 3;
            float2 v = F2[(size_t)(bp * 3 + cp) * NPIX + (size_t)hs * 384 + ws];
            xf[b][c]  = v;
            mag[b][c] = sqrtf(v.x * v.x + v.y * v.y);
        }
    }

    // MLP: lgt[b][j], weights loaded once per o for all 4 b
    float lgt[4][9];
#pragma unroll
    for (int b = 0; b < 4; ++b)
#pragma unroll
        for (int j = 0; j < 9; ++j) lgt[b][j] = ab2[j];
    for (int o = 0; o < 64; ++o) {
        float w0 = aw1[o * 3 + 0], w1 = aw1[o * 3 + 1], w2 = aw1[o * 3 + 2];
        float bb = ab1[o];
        float hv[4];
#pragma unroll
        for (int b = 0; b < 4; ++b)
            hv[b] = fmaxf(bb + w0 * mag[b][0] + w1 * mag[b][1] + w2 * mag[b][2], 0.0f);
#pragma unroll
        for (int j = 0; j < 9; ++j) {
            float wj = aw2[j * 64 + o];
#pragma unroll
            for (int b = 0; b < 4; ++b) lgt[b][j] += wj * hv[b];
        }
    }

    // log-Gabor bank at this pixel
    float yy = -1.0f + 2.0f * (float)h / 383.0f;
    float xx = -1.0f + 2.0f * (float)w / 383.0f;
    float r   = sqrtf(xx * xx + yy * yy + 1e-6f);
    float phi = atan2f(yy, xx);
    float filt[3][3][3];
#pragma unroll
    for (int s = 0; s < 3; ++s)
#pragma unroll
        for (int co = 0; co < 3; ++co)
#pragma unroll
            for (int d = 0; d < 3; ++d) {
                int idx = (s * 3 + co) * 3 + d;
                float lf0 = logf(f0[idx]);
                float ls  = logf(sigma[idx]);
                float lr  = logf(r - lf0);
                float lg  = expf(-(lr * lr) / (2.0f * ls * ls));
                float dphi = phi - theta[idx];
                float t0   = theta0[idx];
                float ang  = expf(-(dphi * dphi) / (2.0f * t0 * t0));
                filt[s][co][d] = lg * ang;
            }

#pragma unroll
    for (int b = 0; b < 4; ++b) {
        float mxv = lgt[b][0];
#pragma unroll
        for (int j = 1; j < 9; ++j) mxv = fmaxf(mxv, lgt[b][j]);
        float e[9];
        float se = 0.0f;
#pragma unroll
        for (int j = 0; j < 9; ++j) { e[j] = expf(lgt[b][j] - mxv); se += e[j]; }
        float inv = 1.0f / se;

        float2 acc = make_float2(0.0f, 0.0f);
#pragma unroll
        for (int d = 0; d < 3; ++d) {
            float wg = 0.0f;
#pragma unroll
            for (int s = 0; s < 3; ++s)
#pragma unroll
                for (int co = 0; co < 3; ++co)
                    wg += e[s * 3 + co] * filt[s][co][d];
            wg *= inv;
            acc.x += xf[b][d].x * wg;
            acc.y += xf[b][d].y * wg;
        }
        A[(size_t)b * NPIX + p] = acc;
    }
}

// ---------------------------------------------------------------------------
// K6: 3x3 conv, pad 1. xsp[b][o][h][w]
// ---------------------------------------------------------------------------
__global__ __launch_bounds__(256) void k_conv(const float* __restrict__ x,
                                              const float* __restrict__ cw,
                                              float* __restrict__ xsp) {
    int p = blockIdx.x * 256 + threadIdx.x;
    int w = p % 384;
    int t = p / 384;
    int h = t % 384; t /= 384;
    int o = t % 3;
    int b = t / 3;
    float acc = 0.0f;
    const float* xb = x + (size_t)b * 3 * NPIX;
#pragma unroll
    for (int ci = 0; ci < 3; ++ci) {
        const float* xc = xb + (size_t)ci * NPIX;
#pragma unroll
        for (int kh = 0; kh < 3; ++kh) {
            int hh = h + kh - 1;
            if (hh < 0 || hh >= 384) continue;
#pragma unroll
            for (int kw = 0; kw < 3; ++kw) {
                int ww = w + kw - 1;
                if (ww < 0 || ww >= 384) continue;
                acc += xc[(size_t)hh * 384 + ww] * cw[((o * 3 + ci) * 3 + kh) * 3 + kw];
            }
        }
    }
    xsp[p] = acc;
}

// ---------------------------------------------------------------------------
// K4': masked inverse ROW FFTs, band rows only, compact output.
// G1c[ii][h'-sidx][w] stores (-1)^w * row-ifft (unnormalized).
// ---------------------------------------------------------------------------
__global__ __launch_bounds__(256) void k_masked_rows(const float2* __restrict__ A,
                                                     const float* __restrict__ band,
                                                     float2* __restrict__ G1c) {
    int ii  = blockIdx.y;                  // 0..35
    int rg  = blockIdx.x;                  // 0..23
    int cop = ii / 12;
    int bp  = (ii / 3) % 4;
    int dp  = ii % 3;
    int pidx = (cop * 3 + dp) * 2;
    int sidx = (int)floorf((band[pidx + 0] + 1.0f) * 0.5f * 384.0f);
    int eidx = (int)floorf((band[pidx + 1] + 1.0f) * 0.5f * 384.0f);
    if (eidx <= sidx) return;
    int h0 = 192 + rg * 8;
    if (h0 + 8 <= sidx || h0 >= eidx) return;

    __shared__ float2 sbuf[2][LINES * LSTRIDE];
    int tid = threadIdx.x;
    const float2* Ab = A + (size_t)bp * NPIX;
    for (int idx = tid; idx < 8 * 384; idx += 256) {
        int line = idx / 384;
        int w    = idx - line * 384;
        int h    = h0 + line;
        bool m = (h >= sidx) && (h < eidx) && (w >= sidx) && (w < eidx);
        float2 v = make_float2(0.0f, 0.0f);
        if (m) v = Ab[(size_t)h * 384 + w];
        sbuf[0][line * LSTRIDE + w] = v;
    }
    __syncthreads();
    fft384x8<1>(sbuf[0], sbuf[1], tid);
    for (int idx = tid; idx < 8 * 384; idx += 256) {
        int line = idx / 384;
        int w    = idx - line * 384;
        int h    = h0 + line;
        if (h >= sidx && h < eidx) {
            float2 v = sbuf[0][line * LSTRIDE + w];
            if (w & 1) { v.x = -v.x; v.y = -v.y; }
            G1c[((size_t)ii * 192 + (h - sidx)) * 384 + w] = v;
        }
    }
}

// ---------------------------------------------------------------------------
// K5'': column DFT over band rows + combine, register-tiled 4h x 4w per
// thread, float4 coalesced stores, no LDS, exact integer twiddle phase.
// grid: (36 blocks/image, 36 images). 256 thr: tid -> wq = tid%96, hg = tid/96.
// ---------------------------------------------------------------------------
__global__ __launch_bounds__(256) void k_col_gemm_combine(const float2* __restrict__ G1c,
                                                          const float* __restrict__ band,
                                                          const float* __restrict__ xsp,
                                                          const float* __restrict__ mixing,
                                                          float* __restrict__ out) {
    int ii  = blockIdx.y;
    int gt  = blockIdx.x * 256 + threadIdx.x;   // 0..9215
    int wq  = gt % 96;
    int hg  = gt / 96;
    int w   = wq * 4;
    int h0  = hg * 4;

    int cop = ii / 12;
    int bp  = (ii / 3) % 4;
    int dp  = ii % 3;
    int pidx = (cop * 3 + dp) * 2;
    int sidx = (int)floorf((band[pidx + 0] + 1.0f) * 0.5f * 384.0f);
    int eidx = (int)floorf((band[pidx + 1] + 1.0f) * 0.5f * 384.0f);

    float acc[4][4];
#pragma unroll
    for (int kh = 0; kh < 4; ++kh)
#pragma unroll
        for (int j = 0; j < 4; ++j) acc[kh][j] = 0.0f;

    // g1 row hp at float4 granularity: row stride = 384 float2 = 192 float4
    const float4* g = (const float4*)(G1c + (size_t)ii * 192 * 384 + w);
    for (int hp = sidx; hp < eidx; ++hp) {
        float4 g0 = g[(size_t)(hp - sidx) * 192];       // re0,im0,re1,im1
        float4 g1 = g[(size_t)(hp - sidx) * 192 + 1];   // re2,im2,re3,im3
        int k0 = (hp * h0) % 384;                       // exact phase
        float sn, cs;
        sincospif((float)k0 * (2.0f / 384.0f), &sn, &cs);
        float tx = cs, ty = sn;
        float ssn, scs;
        sincospif((float)hp * (2.0f / 384.0f), &ssn, &scs);
#pragma unroll
        for (int kh = 0; kh < 4; ++kh) {
            acc[kh][0] += tx * g0.x - ty * g0.y;
            acc[kh][1] += tx * g0.z - ty * g0.w;
            acc[kh][2] += tx * g1.x - ty * g1.y;
            acc[kh][3] += tx * g1.z - ty * g1.w;
            float ntx = tx * scs - ty * ssn;            // rotate to h+1
            ty = tx * ssn + ty * scs;
            tx = ntx;
        }
    }

    int co = cop + 2; if (co >= 3) co -= 3;
    int b  = (bp + 2) & 3;
    int d  = dp + 2;  if (d >= 3) d -= 3;
    float mix  = mixing[0];
    float omix = 1.0f - mix;
    const float invn2 = 1.0f / 147456.0f;
    const float* xs = xsp + (size_t)(b * 3 + d) * NPIX;
    float* obase = out + (size_t)(co * 12 + b * 3 + d) * NPIX;
#pragma unroll
    for (int kh = 0; kh < 4; ++kh) {
        int h = h0 + kh;
        float sgn = (h & 1) ? -invn2 : invn2;           // fold (-1)^h / N^2
        size_t off = (size_t)h * 384 + w;
        float4 xv = *(const float4*)(xs + off);
        float4 val;
        val.x = mix * (acc[kh][0] * sgn) + omix * xv.x;
        val.y = mix * (acc[kh][1] * sgn) + omix * xv.y;
        val.z = mix * (acc[kh][2] * sgn) + omix * xv.z;
        val.w = mix * (acc[kh][3] * sgn) + omix * xv.w;
#pragma unroll
        for (int a = 0; a < 4; ++a)
            *(float4*)(obase + off + (size_t)a * 5308416) = val;  // a stride = 36*NPIX
    }
}

// ---------------------------------------------------------------------------
extern "C" void kernel_launch(void* const* d_in, const int* in_sizes, int n_in,
                              void* d_out, int out_size, void* d_ws, size_t ws_size,
                              hipStream_t stream) {
    const float* x      = (const float*)d_in[0];
    const float* theta  = (const float*)d_in[1];
    const float* sigma  = (const float*)d_in[2];
    const float* f0     = (const float*)d_in[3];
    const float* theta0 = (const float*)d_in[4];
    const float* aw1    = (const float*)d_in[5];
    const float* ab1    = (const float*)d_in[6];
    const float* aw2    = (const float*)d_in[7];
    const float* ab2    = (const float*)d_in[8];
    const float* cw     = (const float*)d_in[9];
    const float* mixing = (const float*)d_in[10];
    const float* band   = (const float*)d_in[11];
    float* out = (float*)d_out;

    // Workspace layout (float2 units), with reuse:
    //   [0, 12*NPIX)   F1 (dead after K2)   \  overlaid by G1c [0, 18*NPIX)
    //   [12, 24*NPIX)  F2 (dead after K3)   /
    //   [36, 40*NPIX)  A  (attended, shifted frame)
    //   [40*NPIX ...)  xsp (12*NPIX floats)
    float2* F1  = (float2*)d_ws;
    float2* F2  = F1 + (size_t)12 * NPIX;
    float2* G1c = (float2*)d_ws;
    float2* A   = (float2*)d_ws + (size_t)36 * NPIX;
    float*  xsp = (float*)((float2*)d_ws + (size_t)40 * NPIX);

    k_fwd_rows<<<dim3(48, 12), 256, 0, stream>>>(x, F1);
    k_fwd_cols<<<dim3(48, 12), 256, 0, stream>>>(F1, F2);
    k_attn<<<576, 256, 0, stream>>>(F2, theta, sigma, f0, theta0,
                                    aw1, ab1, aw2, ab2, A);
    k_conv<<<6912, 256, 0, stream>>>(x, cw, xsp);
    k_masked_rows<<<dim3(24, 36), 256, 0, stream>>>(A, band, G1c);
    k_col_gemm_combine<<<dim3(36, 36), 256, 0, stream>>>(G1c, band, xsp, mixing, out);
}

// Round 4
// 240.246 us; speedup vs baseline: 1.3309x; 1.0708x over previous
//
#include <hip/hip_runtime.h>
#include <math.h>

// Problem constants
#define N384 384
#define NPIX 147456            // 384*384
#define LSTRIDE 385            // padded LDS line stride (float2) to break bank alignment
#define LINES 8                // lines (rows or cols) per block

__device__ __forceinline__ float2 cmul(float2 a, float2 b) {
    return make_float2(a.x*b.x - a.y*b.y, a.x*b.y + a.y*b.x);
}

// ---------------------------------------------------------------------------
// Build LDS twiddle table tw[k] = (cos, sin)(2*pi*k/384), k in [0,384).
// 1.5 sincospif per thread instead of ~46 per butterfly chain.
// ---------------------------------------------------------------------------
__device__ __forceinline__ void build_tw(float2* tw, int tid) {
    for (int k = tid; k < 384; k += 256) {
        float sn, cs;
        sincospif((float)k * (2.0f / 384.0f), &sn, &cs);
        tw[k] = make_float2(cs, sn);
    }
}

// ---------------------------------------------------------------------------
// In-LDS batched 384-point Stockham FFT, 8 lines per 256-thread block,
// twiddles from LDS table (SGN folded at compile time). Data starts in b0,
// ends in b0. Caller must __syncthreads() after loading b0 + building tw.
// ---------------------------------------------------------------------------
template <int SGNI>
__device__ void fft384x8(float2* b0, float2* b1, const float2* tw, int tid) {
    float2* src = b0;
    float2* dst = b1;
    const int line = tid >> 5;   // 0..7
    const int l32  = tid & 31;   // 0..31

    // ---- radix-3 stage: n=384, s=1, 128 butterflies/line ----
    {
        const float s3 = (float)SGNI * 0.86602540378443864676f;
        float2* L = src + line * LSTRIDE;
        float2* D = dst + line * LSTRIDE;
#pragma unroll
        for (int q = 0; q < 4; ++q) {
            int j = l32 + 32 * q;                  // 0..127
            float2 a0 = L[j], a1 = L[j + 128], a2 = L[j + 256];
            float t1x = a1.x + a2.x, t1y = a1.y + a2.y;
            float t2x = a1.x - a2.x, t2y = a1.y - a2.y;
            float2 bb0 = make_float2(a0.x + t1x, a0.y + t1y);
            float mx = a0.x - 0.5f * t1x, my = a0.y - 0.5f * t1y;
            float ux = -s3 * t2y, uy = s3 * t2x;
            float2 bb1 = make_float2(mx + ux, my + uy);
            float2 bb2 = make_float2(mx - ux, my - uy);
            float2 t  = tw[j];
            float2 t2 = tw[2 * j];
            float2 w  = make_float2(t.x,  (float)SGNI * t.y);
            float2 w2 = make_float2(t2.x, (float)SGNI * t2.y);
            D[3 * j]     = bb0;
            D[3 * j + 1] = cmul(bb1, w);
            D[3 * j + 2] = cmul(bb2, w2);
        }
    }
    __syncthreads();
    { float2* t = src; src = dst; dst = t; }

    // ---- 7 radix-2 stages: twiddle e^{SGN*2pi i j/n} = tw[j*3*2^st] ----
#pragma unroll
    for (int st = 0; st < 7; ++st) {
        const int s  = 3 << st;
        const int n2 = 64 >> st;                   // n/2
        float2* L = src + line * LSTRIDE;
        float2* D = dst + line * LSTRIDE;
#pragma unroll
        for (int q = 0; q < 6; ++q) {
            int i = l32 + 32 * q;                  // 0..191
            int j = i / s;
            int k = i - j * s;
            float2 a = L[k + s * j];
            float2 b = L[k + s * j + s * n2];
            float2 t = tw[j * s];                  // j*3<<st < 384 always
            float2 w = make_float2(t.x, (float)SGNI * t.y);
            float2 sum = make_float2(a.x + b.x, a.y + b.y);
            float2 dif = make_float2(a.x - b.x, a.y - b.y);
            D[k + s * (2 * j)]     = sum;
            D[k + s * (2 * j) + s] = cmul(dif, w);
        }
        __syncthreads();
        { float2* t = src; src = dst; dst = t; }
    }
}

// ---------------------------------------------------------------------------
// K1: forward row FFT of x (real input). 12 images x 48 row-groups.
// float4 global I/O.
// ---------------------------------------------------------------------------
__global__ __launch_bounds__(256) void k_fwd_rows(const float* __restrict__ x,
                                                  float2* __restrict__ F1) {
    __shared__ float2 sbuf[2][LINES * LSTRIDE];
    __shared__ float2 tw[384];
    int img = blockIdx.y;
    int rg  = blockIdx.x;
    int tid = threadIdx.x;
    build_tw(tw, tid);
    const float4* xim = (const float4*)(x + (size_t)img * NPIX + (size_t)rg * 8 * 384);
    for (int idx4 = tid; idx4 < 768; idx4 += 256) {      // 768 float4 = 8*384 floats
        int line = idx4 / 96;
        int e    = (idx4 - line * 96) * 4;
        float4 v = xim[idx4];
        float2* L = sbuf[0] + line * LSTRIDE + e;
        L[0] = make_float2(v.x, 0.0f);
        L[1] = make_float2(v.y, 0.0f);
        L[2] = make_float2(v.z, 0.0f);
        L[3] = make_float2(v.w, 0.0f);
    }
    __syncthreads();
    fft384x8<-1>(sbuf[0], sbuf[1], tw, tid);
    float4* o = (float4*)(F1 + (size_t)img * NPIX + (size_t)rg * 8 * 384);
    for (int idx4 = tid; idx4 < 1536; idx4 += 256) {     // 1536 float4 = 8*384 float2
        int line = idx4 / 192;
        int e2   = (idx4 - line * 192) * 2;
        float2 a = sbuf[0][line * LSTRIDE + e2];
        float2 b = sbuf[0][line * LSTRIDE + e2 + 1];
        o[idx4] = make_float4(a.x, a.y, b.x, b.y);
    }
}

// ---------------------------------------------------------------------------
// K2: forward column FFT. 12 images x 48 col-groups (8 cols each).
// ---------------------------------------------------------------------------
__global__ __launch_bounds__(256) void k_fwd_cols(const float2* __restrict__ In,
                                                  float2* __restrict__ Out) {
    __shared__ float2 sbuf[2][LINES * LSTRIDE];
    __shared__ float2 tw[384];
    int img = blockIdx.y;
    int cg  = blockIdx.x;
    int tid = threadIdx.x;
    build_tw(tw, tid);
    const float2* inim = In + (size_t)img * NPIX + cg * 8;
    int c = tid & 7, hb = tid >> 3;
    for (int q = 0; q < 12; ++q) {
        int h = hb + 32 * q;
        sbuf[0][c * LSTRIDE + h] = inim[(size_t)h * 384 + c];
    }
    __syncthreads();
    fft384x8<-1>(sbuf[0], sbuf[1], tw, tid);
    float2* outim = Out + (size_t)img * NPIX + cg * 8;
    for (int q = 0; q < 12; ++q) {
        int h = hb + 32 * q;
        outim[(size_t)h * 384 + c] = sbuf[0][c * LSTRIDE + h];
    }
}

// ---------------------------------------------------------------------------
// K3: per-pixel attention MLP + log-Gabor filter bank -> attended[4,H,W]
// (stored in the SHIFTED frame). Param transcendentals hoisted to LDS
// (27 tuples), Gaussian pair fused into one expf.
// ---------------------------------------------------------------------------
__global__ __launch_bounds__(256) void k_attn(const float2* __restrict__ F2,
                                              const float* __restrict__ theta,
                                              const float* __restrict__ sigma,
                                              const float* __restrict__ f0,
                                              const float* __restrict__ theta0,
                                              const float* __restrict__ aw1,
                                              const float* __restrict__ ab1,
                                              const float* __restrict__ aw2,
                                              const float* __restrict__ ab2,
                                              float2* __restrict__ A) {
    __shared__ float4 par[27];     // (lf0, -1/(2 ln^2 sigma), theta, -1/(2 theta0^2))
    int tid = threadIdx.x;
    if (tid < 27) {
        float lf0 = logf(f0[tid]);
        float ls  = logf(sigma[tid]);
        float na  = -0.5f / (ls * ls);
        float th  = theta[tid];
        float t0  = theta0[tid];
        float nb  = -0.5f / (t0 * t0);
        par[tid] = make_float4(lf0, na, th, nb);
    }
    __syncthreads();

    int p = blockIdx.x * 256 + tid;
    int h = p / 384;
    int w = p - h * 384;
    int hs = h + 192; if (hs >= 384) hs -= 384;
    int ws = w + 192; if (ws >= 384) ws -= 384;

    float2 xf[4][3];
    float  mag[4][3];
#pragma unroll
    for (int b = 0; b < 4; ++b) {
        int bp = (b + 2) & 3;
#pragma unroll
        for (int c = 0; c < 3; ++c) {
            int cp = c + 2; if (cp >= 3) cp -= 3;
            float2 v = F2[(size_t)(bp * 3 + cp) * NPIX + (size_t)hs * 384 + ws];
            xf[b][c]  = v;
            mag[b][c] = sqrtf(v.x * v.x + v.y * v.y);
        }
    }

    // MLP: lgt[b][j], weights loaded once per o for all 4 b
    float lgt[4][9];
#pragma unroll
    for (int b = 0; b < 4; ++b)
#pragma unroll
        for (int j = 0; j < 9; ++j) lgt[b][j] = ab2[j];
    for (int o = 0; o < 64; ++o) {
        float w0 = aw1[o * 3 + 0], w1 = aw1[o * 3 + 1], w2 = aw1[o * 3 + 2];
        float bb = ab1[o];
        float hv[4];
#pragma unroll
        for (int b = 0; b < 4; ++b)
            hv[b] = fmaxf(bb + w0 * mag[b][0] + w1 * mag[b][1] + w2 * mag[b][2], 0.0f);
#pragma unroll
        for (int j = 0; j < 9; ++j) {
            float wj = aw2[j * 64 + o];
#pragma unroll
            for (int b = 0; b < 4; ++b) lgt[b][j] += wj * hv[b];
        }
    }

    // log-Gabor bank at this pixel (one expf per filter)
    float yy = -1.0f + 2.0f * (float)h / 383.0f;
    float xx = -1.0f + 2.0f * (float)w / 383.0f;
    float r   = sqrtf(xx * xx + yy * yy + 1e-6f);
    float phi = atan2f(yy, xx);
    float filt[27];
#pragma unroll
    for (int i = 0; i < 27; ++i) {
        float4 pr = par[i];                 // LDS broadcast
        float lr = logf(r - pr.x);
        float dphi = phi - pr.z;
        filt[i] = expf(lr * lr * pr.y + dphi * dphi * pr.w);
    }

#pragma unroll
    for (int b = 0; b < 4; ++b) {
        float mxv = lgt[b][0];
#pragma unroll
        for (int j = 1; j < 9; ++j) mxv = fmaxf(mxv, lgt[b][j]);
        float e[9];
        float se = 0.0f;
#pragma unroll
        for (int j = 0; j < 9; ++j) { e[j] = expf(lgt[b][j] - mxv); se += e[j]; }
        float inv = 1.0f / se;

        float2 acc = make_float2(0.0f, 0.0f);
#pragma unroll
        for (int d = 0; d < 3; ++d) {
            float wg = 0.0f;
#pragma unroll
            for (int s = 0; s < 3; ++s)
#pragma unroll
                for (int co = 0; co < 3; ++co)
                    wg += e[s * 3 + co] * filt[(s * 3 + co) * 3 + d];
            wg *= inv;
            acc.x += xf[b][d].x * wg;
            acc.y += xf[b][d].y * wg;
        }
        A[(size_t)b * NPIX + p] = acc;
    }
}

// ---------------------------------------------------------------------------
// K6: 3x3 conv, pad 1. xsp[b][o][h][w]
// ---------------------------------------------------------------------------
__global__ __launch_bounds__(256) void k_conv(const float* __restrict__ x,
                                              const float* __restrict__ cw,
                                              float* __restrict__ xsp) {
    int p = blockIdx.x * 256 + threadIdx.x;
    int w = p % 384;
    int t = p / 384;
    int h = t % 384; t /= 384;
    int o = t % 3;
    int b = t / 3;
    float acc = 0.0f;
    const float* xb = x + (size_t)b * 3 * NPIX;
#pragma unroll
    for (int ci = 0; ci < 3; ++ci) {
        const float* xc = xb + (size_t)ci * NPIX;
#pragma unroll
        for (int kh = 0; kh < 3; ++kh) {
            int hh = h + kh - 1;
            if (hh < 0 || hh >= 384) continue;
#pragma unroll
            for (int kw = 0; kw < 3; ++kw) {
                int ww = w + kw - 1;
                if (ww < 0 || ww >= 384) continue;
                acc += xc[(size_t)hh * 384 + ww] * cw[((o * 3 + ci) * 3 + kh) * 3 + kw];
            }
        }
    }
    xsp[p] = acc;
}

// ---------------------------------------------------------------------------
// K4': masked inverse ROW FFTs, band rows only, compact output.
// G1c[ii][h'-sidx][w] stores (-1)^w * row-ifft (unnormalized).
// ---------------------------------------------------------------------------
__global__ __launch_bounds__(256) void k_masked_rows(const float2* __restrict__ A,
                                                     const float* __restrict__ band,
                                                     float2* __restrict__ G1c) {
    int ii  = blockIdx.y;                  // 0..35
    int rg  = blockIdx.x;                  // 0..23
    int cop = ii / 12;
    int bp  = (ii / 3) % 4;
    int dp  = ii % 3;
    int pidx = (cop * 3 + dp) * 2;
    int sidx = (int)floorf((band[pidx + 0] + 1.0f) * 0.5f * 384.0f);
    int eidx = (int)floorf((band[pidx + 1] + 1.0f) * 0.5f * 384.0f);
    if (eidx <= sidx) return;
    int h0 = 192 + rg * 8;
    if (h0 + 8 <= sidx || h0 >= eidx) return;

    __shared__ float2 sbuf[2][LINES * LSTRIDE];
    __shared__ float2 tw[384];
    int tid = threadIdx.x;
    build_tw(tw, tid);
    const float2* Ab = A + (size_t)bp * NPIX;
    for (int idx = tid; idx < 8 * 384; idx += 256) {
        int line = idx / 384;
        int w    = idx - line * 384;
        int h    = h0 + line;
        bool m = (h >= sidx) && (h < eidx) && (w >= sidx) && (w < eidx);
        float2 v = make_float2(0.0f, 0.0f);
        if (m) v = Ab[(size_t)h * 384 + w];
        sbuf[0][line * LSTRIDE + w] = v;
    }
    __syncthreads();
    fft384x8<1>(sbuf[0], sbuf[1], tw, tid);
    for (int idx = tid; idx < 8 * 384; idx += 256) {
        int line = idx / 384;
        int w    = idx - line * 384;
        int h    = h0 + line;
        if (h >= sidx && h < eidx) {
            float2 v = sbuf[0][line * LSTRIDE + w];
            if (w & 1) { v.x = -v.x; v.y = -v.y; }
            G1c[((size_t)ii * 192 + (h - sidx)) * 384 + w] = v;
        }
    }
}

// ---------------------------------------------------------------------------
// K5'': column DFT over band rows + combine, register-tiled 4h x 4w per
// thread, float4 coalesced stores, no LDS, exact integer twiddle phase.
// ---------------------------------------------------------------------------
__global__ __launch_bounds__(256) void k_col_gemm_combine(const float2* __restrict__ G1c,
                                                          const float* __restrict__ band,
                                                          const float* __restrict__ xsp,
                                                          const float* __restrict__ mixing,
                                                          float* __restrict__ out) {
    int ii  = blockIdx.y;
    int gt  = blockIdx.x * 256 + threadIdx.x;   // 0..9215
    int wq  = gt % 96;
    int hg  = gt / 96;
    int w   = wq * 4;
    int h0  = hg * 4;

    int cop = ii / 12;
    int bp  = (ii / 3) % 4;
    int dp  = ii % 3;
    int pidx = (cop * 3 + dp) * 2;
    int sidx = (int)floorf((band[pidx + 0] + 1.0f) * 0.5f * 384.0f);
    int eidx = (int)floorf((band[pidx + 1] + 1.0f) * 0.5f * 384.0f);

    float acc[4][4];
#pragma unroll
    for (int kh = 0; kh < 4; ++kh)
#pragma unroll
        for (int j = 0; j < 4; ++j) acc[kh][j] = 0.0f;

    const float4* g = (const float4*)(G1c + (size_t)ii * 192 * 384 + w);
    for (int hp = sidx; hp < eidx; ++hp) {
        float4 g0 = g[(size_t)(hp - sidx) * 192];       // re0,im0,re1,im1
        float4 g1 = g[(size_t)(hp - sidx) * 192 + 1];   // re2,im2,re3,im3
        int k0 = (hp * h0) % 384;                       // exact phase
        float sn, cs;
        sincospif((float)k0 * (2.0f / 384.0f), &sn, &cs);
        float tx = cs, ty = sn;
        float ssn, scs;
        sincospif((float)hp * (2.0f / 384.0f), &ssn, &scs);
#pragma unroll
        for (int kh = 0; kh < 4; ++kh) {
            acc[kh][0] += tx * g0.x - ty * g0.y;
            acc[kh][1] += tx * g0.z - ty * g0.w;
            acc[kh][2] += tx * g1.x - ty * g1.y;
            acc[kh][3] += tx * g1.z - ty * g1.w;
            float ntx = tx * scs - ty * ssn;            // rotate to h+1
            ty = tx * ssn + ty * scs;
            tx = ntx;
        }
    }

    int co = cop + 2; if (co >= 3) co -= 3;
    int b  = (bp + 2) & 3;
    int d  = dp + 2;  if (d >= 3) d -= 3;
    float mix  = mixing[0];
    float omix = 1.0f - mix;
    const float invn2 = 1.0f / 147456.0f;
    const float* xs = xsp + (size_t)(b * 3 + d) * NPIX;
    float* obase = out + (size_t)(co * 12 + b * 3 + d) * NPIX;
#pragma unroll
    for (int kh = 0; kh < 4; ++kh) {
        int h = h0 + kh;
        float sgn = (h & 1) ? -invn2 : invn2;           // fold (-1)^h / N^2
        size_t off = (size_t)h * 384 + w;
        float4 xv = *(const float4*)(xs + off);
        float4 val;
        val.x = mix * (acc[kh][0] * sgn) + omix * xv.x;
        val.y = mix * (acc[kh][1] * sgn) + omix * xv.y;
        val.z = mix * (acc[kh][2] * sgn) + omix * xv.z;
        val.w = mix * (acc[kh][3] * sgn) + omix * xv.w;
#pragma unroll
        for (int a = 0; a < 4; ++a)
            *(float4*)(obase + off + (size_t)a * 5308416) = val;  // a stride = 36*NPIX
    }
}

// ---------------------------------------------------------------------------
extern "C" void kernel_launch(void* const* d_in, const int* in_sizes, int n_in,
                              void* d_out, int out_size, void* d_ws, size_t ws_size,
                              hipStream_t stream) {
    const float* x      = (const float*)d_in[0];
    const float* theta  = (const float*)d_in[1];
    const float* sigma  = (const float*)d_in[2];
    const float* f0     = (const float*)d_in[3];
    const float* theta0 = (const float*)d_in[4];
    const float* aw1    = (const float*)d_in[5];
    const float* ab1    = (const float*)d_in[6];
    const float* aw2    = (const float*)d_in[7];
    const float* ab2    = (const float*)d_in[8];
    const float* cw     = (const float*)d_in[9];
    const float* mixing = (const float*)d_in[10];
    const float* band   = (const float*)d_in[11];
    float* out = (float*)d_out;

    // Workspace layout (float2 units), with reuse:
    //   [0, 12*NPIX)   F1 (dead after K2)   \  overlaid by G1c [0, 18*NPIX)
    //   [12, 24*NPIX)  F2 (dead after K3)   /
    //   [36, 40*NPIX)  A  (attended, shifted frame)
    //   [40*NPIX ...)  xsp (12*NPIX floats)
    float2* F1  = (float2*)d_ws;
    float2* F2  = F1 + (size_t)12 * NPIX;
    float2* G1c = (float2*)d_ws;
    float2* A   = (float2*)d_ws + (size_t)36 * NPIX;
    float*  xsp = (float*)((float2*)d_ws + (size_t)40 * NPIX);

    k_fwd_rows<<<dim3(48, 12), 256, 0, stream>>>(x, F1);
    k_fwd_cols<<<dim3(48, 12), 256, 0, stream>>>(F1, F2);
    k_attn<<<576, 256, 0, stream>>>(F2, theta, sigma, f0, theta0,
                                    aw1, ab1, aw2, ab2, A);
    k_conv<<<6912, 256, 0, stream>>>(x, cw, xsp);
    k_masked_rows<<<dim3(24, 36), 256, 0, stream>>>(A, band, G1c);
    k_col_gemm_combine<<<dim3(36, 36), 256, 0, stream>>>(G1c, band, xsp, mixing, out);
}